// Round 1
// baseline (122.725 us; speedup 1.0000x reference)
//
#include <hip/hip_runtime.h>
#include <math.h>

#define EPSF 1e-8f

typedef __attribute__((ext_vector_type(4))) short short4v;
typedef __attribute__((ext_vector_type(8))) short short8v;
typedef __attribute__((ext_vector_type(4))) float float4v;

__device__ inline short f2bf(float f) {
    unsigned u = __builtin_bit_cast(unsigned, f);
    unsigned r = (u + 0x7FFFu + ((u >> 16) & 1u)) >> 16;
    return (short)r;
}
__device__ inline float bf2f(short s) {
    unsigned u = ((unsigned)(unsigned short)s) << 16;
    return __builtin_bit_cast(float, u);
}

// F layout (bf16 shorts): f1t @0 (4*128*4096), f1s @2097152, f2t @4194304
// (4*256*1024), f2s @5242880; total 6291456 shorts = 12.6 MB.
#define F1T 0
#define F1S 2097152
#define F2T 4194304
#define F2S 5242880

// Sub-tile combos {g, ri, rj, w}; tile unit = 64 rows. g: 0=t*t 1=s*s 2=t*s.
// Diagonal grams symmetric: upper triangle; diag tile w=1, off-diag w=2;
// cross gram w=-2.
__constant__ int g1_tab[10][4] = {      // c=128 -> 2x2 grid of 64-tiles
    {0,0,0,1},{0,0,1,2},{0,1,1,1},
    {1,0,0,1},{1,0,1,2},{1,1,1,1},
    {2,0,0,-2},{2,0,1,-2},{2,1,0,-2},{2,1,1,-2},
};
__constant__ int g2_tab[36][4] = {      // c=256 -> 4x4 grid of 64-tiles
    {0,0,0,1},{0,0,1,2},{0,0,2,2},{0,0,3,2},{0,1,1,1},{0,1,2,2},{0,1,3,2},{0,2,2,1},{0,2,3,2},{0,3,3,1},
    {1,0,0,1},{1,0,1,2},{1,0,2,2},{1,0,3,2},{1,1,1,1},{1,1,2,2},{1,1,3,2},{1,2,2,1},{1,2,3,2},{1,3,3,1},
    {2,0,0,-2},{2,0,1,-2},{2,0,2,-2},{2,0,3,-2},
    {2,1,0,-2},{2,1,1,-2},{2,1,2,-2},{2,1,3,-2},
    {2,2,0,-2},{2,2,1,-2},{2,2,2,-2},{2,2,3,-2},
    {2,3,0,-2},{2,3,1,-2},{2,3,2,-2},{2,3,3,-2},
};

// ------------- prep: single-pass norm + normalize + bf16 convert -----------
// 1280 blocks x 32 px. 8 px-groups x 32 channel-slices. Raw values stashed
// in registers as packed bf16; inputs read ONCE.
template<int C, int HW>
__device__ inline void prep_body(const float* __restrict__ x,
                                 short* __restrict__ f, int lp, int t)
{
    const int lanei = t & 7, slice = t >> 3;     // 8 groups x 32 slices
    const int b = lp / HW, m = lp - b * HW;
    const float* p = x + (size_t)b * C * HW + m;
    short*       q = f + (size_t)b * C * HW + m;
    constexpr int CPR = C >> 5;          // rows per slice (4 or 8)
    short4v vals[CPR];
    float4 s0 = {0.f,0.f,0.f,0.f}, s1 = {0.f,0.f,0.f,0.f};
#pragma unroll
    for (int i = 0; i < CPR; i += 2) {
        float4 v0 = *(const float4*)(p + (size_t)(slice * CPR + i)     * HW);
        float4 v1 = *(const float4*)(p + (size_t)(slice * CPR + i + 1) * HW);
        s0.x += v0.x * v0.x; s0.y += v0.y * v0.y;
        s0.z += v0.z * v0.z; s0.w += v0.w * v0.w;
        s1.x += v1.x * v1.x; s1.y += v1.y * v1.y;
        s1.z += v1.z * v1.z; s1.w += v1.w * v1.w;
        vals[i]     = (short4v){ f2bf(v0.x), f2bf(v0.y), f2bf(v0.z), f2bf(v0.w) };
        vals[i + 1] = (short4v){ f2bf(v1.x), f2bf(v1.y), f2bf(v1.z), f2bf(v1.w) };
    }
    float4 s = { s0.x + s1.x, s0.y + s1.y, s0.z + s1.z, s0.w + s1.w };
    __shared__ float4 red[32][8];
    __shared__ float4 invl[8];
    red[slice][lanei] = s;
    __syncthreads();
    if (t < 8) {
        float4 tot = {0.f,0.f,0.f,0.f};
#pragma unroll
        for (int sl = 0; sl < 32; ++sl) {
            float4 v = red[sl][t];
            tot.x += v.x; tot.y += v.y; tot.z += v.z; tot.w += v.w;
        }
        invl[t] = (float4){ 1.f / (sqrtf(tot.x) + EPSF), 1.f / (sqrtf(tot.y) + EPSF),
                            1.f / (sqrtf(tot.z) + EPSF), 1.f / (sqrtf(tot.w) + EPSF) };
    }
    __syncthreads();
    const float4 iv = invl[lanei];
#pragma unroll
    for (int i = 0; i < CPR; ++i) {
        const int r = slice * CPR + i;
        short4v rv = vals[i];
        short4v o = { f2bf(bf2f(rv[0]) * iv.x), f2bf(bf2f(rv[1]) * iv.y),
                      f2bf(bf2f(rv[2]) * iv.z), f2bf(bf2f(rv[3]) * iv.w) };
        *(short4v*)(q + (size_t)r * HW) = o;
    }
}

__global__ __launch_bounds__(256) void prep_kernel(
    const float* __restrict__ x1t, const float* __restrict__ x1s,
    const float* __restrict__ x2t, const float* __restrict__ x2s,
    short* __restrict__ F, float* __restrict__ out)
{
    const int gp = blockIdx.x * 32;
    const int t = threadIdx.x;
    const int lanei = t & 7;
    if (blockIdx.x == 0 && t < 4) out[t] = 0.f;   // replaces memset dispatch
    if (gp < 16384)
        prep_body<128, 4096>(x1t, F + F1T, gp + lanei * 4, t);
    else if (gp < 32768)
        prep_body<128, 4096>(x1s, F + F1S, gp - 16384 + lanei * 4, t);
    else if (gp < 36864)
        prep_body<256, 1024>(x2t, F + F2T, gp - 32768 + lanei * 4, t);
    else
        prep_body<256, 1024>(x2s, F + F2S, gp - 36864 + lanei * 4, t);
}

// ------------- gram tile body: ITERS k-steps of 32 px each ----------------
// unroll 2 -> up to 16 loads in flight per wave; MFMA of step i overlaps the
// loads of step i+1.
template<int HW, int ITERS, bool SHARE>
__device__ inline void gram_accum(const short* __restrict__ Fa,
                                  const short* __restrict__ Fb,
                                  int k0, int lane, float4v (&acc)[4][4])
{
    const int r16 = lane & 15, quad = lane >> 4;
    const int kb = k0 + quad * 8;
#pragma unroll 2
    for (int it = 0; it < ITERS; ++it) {
        short8v af[4], bfr[4];
#pragma unroll
        for (int rt = 0; rt < 4; ++rt)
            af[rt] = *(const short8v*)(
                Fa + (size_t)(rt * 16 + r16) * HW + kb + it * 32);
        if (!SHARE) {
#pragma unroll
            for (int ct = 0; ct < 4; ++ct)
                bfr[ct] = *(const short8v*)(
                    Fb + (size_t)(ct * 16 + r16) * HW + kb + it * 32);
        }
#pragma unroll
        for (int rt = 0; rt < 4; ++rt)
#pragma unroll
            for (int ct = 0; ct < 4; ++ct)
                acc[rt][ct] = __builtin_amdgcn_mfma_f32_16x16x32_bf16(
                    af[rt], SHARE ? af[ct] : bfr[ct], acc[rt][ct], 0, 0, 0);
    }
}

// ------------- fused gram: one block per 64x64 tile, full k ---------------
// 184 blocks x 512 thr (8 waves). g1 (id<40): wave w covers k in
// [w*512,(w+1)*512) -> 16 steps. g2: k in [w*128, ...) -> 4 steps.
// 8 wave-partials combined in LDS (4 rounds, 2 stride-68 buffers), then
// square+weight+reduce in-block; 3 atomicAdds. No partials round-trip.
__global__ __launch_bounds__(512, 2) void gram_kernel(
    const short* __restrict__ F, float* __restrict__ out)
{
    __shared__ float buf[2][64 * 68];    // stride-68: 2-way bank alias (free)
    __shared__ float scratch[8];

    const int id = blockIdx.x;
    const int t = threadIdx.x, w = t >> 6, lane = t & 63;
    const int r16 = lane & 15, quad = lane >> 4;

    float4v acc[4][4];
#pragma unroll
    for (int i = 0; i < 4; ++i)
#pragma unroll
        for (int j = 0; j < 4; ++j) acc[i][j] = (float4v){0.f, 0.f, 0.f, 0.f};

    float wt; int which;
    if (id < 40) {                       // group 1: c=128, hw=4096
        const int comb = id >> 2, b = id & 3;
        const int g = g1_tab[comb][0];
        const int ra = g1_tab[comb][1] << 6, rb = g1_tab[comb][2] << 6;
        const short* Fa = (g == 1 ? F + F1S : F + F1T) + (size_t)(b * 128 + ra) * 4096;
        const short* Fb = (g == 0 ? F + F1T : F + F1S) + (size_t)(b * 128 + rb) * 4096;
        const int k0 = w * 512;
        if (g < 2 && ra == rb) gram_accum<4096, 16, true >(Fa, Fa, k0, lane, acc);
        else                   gram_accum<4096, 16, false>(Fa, Fb, k0, lane, acc);
        wt = (float)g1_tab[comb][3] * (1.0f / (4096.f * 4096.f * 4.f));
        which = 2;
    } else {                             // group 2: c=256, hw=1024
        const int id2 = id - 40;
        const int comb = id2 >> 2, b = id2 & 3;
        const int g = g2_tab[comb][0];
        const int ra = g2_tab[comb][1] << 6, rb = g2_tab[comb][2] << 6;
        const short* Fa = (g == 1 ? F + F2S : F + F2T) + (size_t)(b * 256 + ra) * 1024;
        const short* Fb = (g == 0 ? F + F2T : F + F2S) + (size_t)(b * 256 + rb) * 1024;
        const int k0 = w * 128;
        if (g < 2 && ra == rb) gram_accum<1024, 4, true >(Fa, Fa, k0, lane, acc);
        else                   gram_accum<1024, 4, false>(Fa, Fb, k0, lane, acc);
        wt = (float)g2_tab[comb][3] * (1.0f / (1024.f * 1024.f * 4.f));
        which = 3;
    }

    // ---- combine 8 wave partials (4 rounds, 2 buffers) --------------------
    // C/D layout: col = lane&15, row = quad*4 + reg.
#pragma unroll 1
    for (int rr = 0; rr < 4; ++rr) {
        if ((w >> 1) == rr) {
            float* dst = buf[w & 1];
#pragma unroll
            for (int rt = 0; rt < 4; ++rt)
#pragma unroll
                for (int ct = 0; ct < 4; ++ct)
#pragma unroll
                    for (int r = 0; r < 4; ++r) {
                        int off = (rt * 16 + quad * 4 + r) * 68 + ct * 16 + r16;
                        if (rr == 0) dst[off] = acc[rt][ct][r];
                        else         dst[off] += acc[rt][ct][r];
                    }
        }
        __syncthreads();
    }

    // ---- square + weight + block reduce; 3 atomics ------------------------
    float s = 0.f;
#pragma unroll
    for (int i = 0; i < 8; ++i) {
        int cell = (i << 9) + t;         // 4096 cells / 512 thr
        int off = (cell >> 6) * 68 + (cell & 63);   // row-per-wave: 2-way only
        float v = buf[0][off] + buf[1][off];
        s += v * v;
    }
    s *= wt;
#pragma unroll
    for (int off = 32; off > 0; off >>= 1) s += __shfl_down(s, off);
    if (lane == 0) scratch[w] = s;
    __syncthreads();
    if (t == 0) {
        float v = scratch[0] + scratch[1] + scratch[2] + scratch[3]
                + scratch[4] + scratch[5] + scratch[6] + scratch[7];
        atomicAdd(&out[0], v);           // loss
        atomicAdd(&out[1], v);           // stack[0] = loss
        atomicAdd(&out[which], v);       // stack[1]=pwl_g1 / stack[2]=pwl_g2
    }
}

extern "C" void kernel_launch(void* const* d_in, const int* in_sizes, int n_in,
                              void* d_out, int out_size, void* d_ws, size_t ws_size,
                              hipStream_t stream)
{
    const float* x1t = (const float*)d_in[0];   // [4,128,64,64]
    const float* x1s = (const float*)d_in[1];
    const float* x2t = (const float*)d_in[2];   // [4,256,32,32]
    const float* x2s = (const float*)d_in[3];

    short* F = (short*)d_ws;                    // 6291456 shorts (12.6 MB)

    prep_kernel<<<1280, 256, 0, stream>>>(x1t, x1s, x2t, x2s, F, (float*)d_out);
    gram_kernel<<<184, 512, 0, stream>>>(F, (float*)d_out);
}

// Round 2
// 91.490 us; speedup vs baseline: 1.3414x; 1.3414x over previous
//
#include <hip/hip_runtime.h>
#include <math.h>

#define EPSF 1e-8f

typedef __attribute__((ext_vector_type(4))) short short4v;
typedef __attribute__((ext_vector_type(8))) short short8v;
typedef __attribute__((ext_vector_type(4))) float float4v;

__device__ inline short f2bf(float f) {
    unsigned u = __builtin_bit_cast(unsigned, f);
    unsigned r = (u + 0x7FFFu + ((u >> 16) & 1u)) >> 16;
    return (short)r;
}
__device__ inline float bf2f(short s) {
    unsigned u = ((unsigned)(unsigned short)s) << 16;
    return __builtin_bit_cast(float, u);
}

// F layout (bf16 shorts): f1t @0 (4*128*4096), f1s @2097152, f2t @4194304
// (4*256*1024), f2s @5242880; total 6291456 shorts = 12.6 MB.
#define F1T 0
#define F1S 2097152
#define F2T 4194304
#define F2S 5242880

// Sub-tile combos {g, ri, rj, w}; tile unit = 64 rows. g: 0=t*t 1=s*s 2=t*s.
// Diagonal grams symmetric: upper triangle; diag tile w=1, off-diag w=2;
// cross gram w=-2.
__constant__ int g1_tab[10][4] = {      // c=128 -> 2x2 grid of 64-tiles
    {0,0,0,1},{0,0,1,2},{0,1,1,1},
    {1,0,0,1},{1,0,1,2},{1,1,1,1},
    {2,0,0,-2},{2,0,1,-2},{2,1,0,-2},{2,1,1,-2},
};
__constant__ int g2_tab[36][4] = {      // c=256 -> 4x4 grid of 64-tiles
    {0,0,0,1},{0,0,1,2},{0,0,2,2},{0,0,3,2},{0,1,1,1},{0,1,2,2},{0,1,3,2},{0,2,2,1},{0,2,3,2},{0,3,3,1},
    {1,0,0,1},{1,0,1,2},{1,0,2,2},{1,0,3,2},{1,1,1,1},{1,1,2,2},{1,1,3,2},{1,2,2,1},{1,2,3,2},{1,3,3,1},
    {2,0,0,-2},{2,0,1,-2},{2,0,2,-2},{2,0,3,-2},
    {2,1,0,-2},{2,1,1,-2},{2,1,2,-2},{2,1,3,-2},
    {2,2,0,-2},{2,2,1,-2},{2,2,2,-2},{2,2,3,-2},
    {2,3,0,-2},{2,3,1,-2},{2,3,2,-2},{2,3,3,-2},
};

// ------------- prep: single-pass norm + normalize + bf16 convert -----------
// 1280 blocks x 32 px. 8 px-groups x 32 channel-slices. Raw values stashed
// in registers as packed bf16; inputs read ONCE.
template<int C, int HW>
__device__ inline void prep_body(const float* __restrict__ x,
                                 short* __restrict__ f, int lp, int t)
{
    const int lanei = t & 7, slice = t >> 3;     // 8 groups x 32 slices
    const int b = lp / HW, m = lp - b * HW;
    const float* p = x + (size_t)b * C * HW + m;
    short*       q = f + (size_t)b * C * HW + m;
    constexpr int CPR = C >> 5;          // rows per slice (4 or 8)
    short4v vals[CPR];
    float4 s0 = {0.f,0.f,0.f,0.f}, s1 = {0.f,0.f,0.f,0.f};
#pragma unroll
    for (int i = 0; i < CPR; i += 2) {
        float4 v0 = *(const float4*)(p + (size_t)(slice * CPR + i)     * HW);
        float4 v1 = *(const float4*)(p + (size_t)(slice * CPR + i + 1) * HW);
        s0.x += v0.x * v0.x; s0.y += v0.y * v0.y;
        s0.z += v0.z * v0.z; s0.w += v0.w * v0.w;
        s1.x += v1.x * v1.x; s1.y += v1.y * v1.y;
        s1.z += v1.z * v1.z; s1.w += v1.w * v1.w;
        vals[i]     = (short4v){ f2bf(v0.x), f2bf(v0.y), f2bf(v0.z), f2bf(v0.w) };
        vals[i + 1] = (short4v){ f2bf(v1.x), f2bf(v1.y), f2bf(v1.z), f2bf(v1.w) };
    }
    float4 s = { s0.x + s1.x, s0.y + s1.y, s0.z + s1.z, s0.w + s1.w };
    __shared__ float4 red[32][8];
    __shared__ float4 invl[8];
    red[slice][lanei] = s;
    __syncthreads();
    if (t < 8) {
        float4 tot = {0.f,0.f,0.f,0.f};
#pragma unroll
        for (int sl = 0; sl < 32; ++sl) {
            float4 v = red[sl][t];
            tot.x += v.x; tot.y += v.y; tot.z += v.z; tot.w += v.w;
        }
        invl[t] = (float4){ 1.f / (sqrtf(tot.x) + EPSF), 1.f / (sqrtf(tot.y) + EPSF),
                            1.f / (sqrtf(tot.z) + EPSF), 1.f / (sqrtf(tot.w) + EPSF) };
    }
    __syncthreads();
    const float4 iv = invl[lanei];
#pragma unroll
    for (int i = 0; i < CPR; ++i) {
        const int r = slice * CPR + i;
        short4v rv = vals[i];
        short4v o = { f2bf(bf2f(rv[0]) * iv.x), f2bf(bf2f(rv[1]) * iv.y),
                      f2bf(bf2f(rv[2]) * iv.z), f2bf(bf2f(rv[3]) * iv.w) };
        *(short4v*)(q + (size_t)r * HW) = o;
    }
}

__global__ __launch_bounds__(256) void prep_kernel(
    const float* __restrict__ x1t, const float* __restrict__ x1s,
    const float* __restrict__ x2t, const float* __restrict__ x2s,
    short* __restrict__ F, float* __restrict__ out)
{
    const int gp = blockIdx.x * 32;
    const int t = threadIdx.x;
    const int lanei = t & 7;
    if (blockIdx.x == 0 && t < 4) out[t] = 0.f;   // replaces memset dispatch
    if (gp < 16384)
        prep_body<128, 4096>(x1t, F + F1T, gp + lanei * 4, t);
    else if (gp < 32768)
        prep_body<128, 4096>(x1s, F + F1S, gp - 16384 + lanei * 4, t);
    else if (gp < 36864)
        prep_body<256, 1024>(x2t, F + F2T, gp - 32768 + lanei * 4, t);
    else
        prep_body<256, 1024>(x2s, F + F2S, gp - 36864 + lanei * 4, t);
}

// ------------- gram tile body: LDS-staged, T14 async-stage split ----------
// Block = 64x64 output tile, k-chunk 512 = 4 stages of 128. Stage [64][128]
// tiles into LDS via coalesced 16B/lane loads (reg-staged: next stage's
// global loads issue BEFORE current compute -> latency hidden). LDS row
// stride 136 shorts (272B): b128 frag reads spread 64 lanes over all 32
// banks at the 1KB data-volume floor (zero excess conflict). Waves split
// output 2x2 (32x32 each) -> per-wave acc is complete over k, no LDS
// combine pass needed.
#define LSTR 136

template<int HW, bool SHARE>
__device__ inline void gram_tile(const short* __restrict__ Fa,
                                 const short* __restrict__ Fb,
                                 int k0, int t,
                                 short* __restrict__ ldsA,
                                 short* __restrict__ ldsB,
                                 float4v (&acc)[2][2])
{
    const int lane = t & 63, w = t >> 6;
    const int r16 = lane & 15, quad = lane >> 4;
    const int srow = t >> 4, skc = t & 15;        // stage map: 16 rows x 16 cols
    const int rt2 = (w >> 1) * 2, ct2 = (w & 1) * 2;

    short8v ar[4], br[4];
#pragma unroll
    for (int p = 0; p < 4; ++p)
        ar[p] = *(const short8v*)(Fa + (size_t)(p * 16 + srow) * HW + k0 + skc * 8);
    if (!SHARE) {
#pragma unroll
        for (int p = 0; p < 4; ++p)
            br[p] = *(const short8v*)(Fb + (size_t)(p * 16 + srow) * HW + k0 + skc * 8);
    }

#pragma unroll 1
    for (int st = 0; st < 4; ++st) {
#pragma unroll
        for (int p = 0; p < 4; ++p)
            *(short8v*)(ldsA + (p * 16 + srow) * LSTR + skc * 8) = ar[p];
        if (!SHARE) {
#pragma unroll
            for (int p = 0; p < 4; ++p)
                *(short8v*)(ldsB + (p * 16 + srow) * LSTR + skc * 8) = br[p];
        }
        __syncthreads();
        if (st < 3) {                    // T14: issue next-stage loads early
            const int k1 = k0 + (st + 1) * 128;
#pragma unroll
            for (int p = 0; p < 4; ++p)
                ar[p] = *(const short8v*)(Fa + (size_t)(p * 16 + srow) * HW + k1 + skc * 8);
            if (!SHARE) {
#pragma unroll
                for (int p = 0; p < 4; ++p)
                    br[p] = *(const short8v*)(Fb + (size_t)(p * 16 + srow) * HW + k1 + skc * 8);
            }
        }
        const short* A = ldsA;
        const short* B = SHARE ? ldsA : ldsB;
#pragma unroll
        for (int ks = 0; ks < 4; ++ks) {
            short8v af[2], bf[2];
#pragma unroll
            for (int i = 0; i < 2; ++i)
                af[i] = *(const short8v*)(A + ((rt2 + i) * 16 + r16) * LSTR + ks * 32 + quad * 8);
#pragma unroll
            for (int j = 0; j < 2; ++j)
                bf[j] = *(const short8v*)(B + ((ct2 + j) * 16 + r16) * LSTR + ks * 32 + quad * 8);
#pragma unroll
            for (int i = 0; i < 2; ++i)
#pragma unroll
                for (int j = 0; j < 2; ++j)
                    acc[i][j] = __builtin_amdgcn_mfma_f32_16x16x32_bf16(
                        af[i], bf[j], acc[i][j], 0, 0, 0);
        }
        __syncthreads();
    }
}

// ------------- stage A: 608 blocks x 256 thr (round-0 geometry) -----------
__global__ __launch_bounds__(256, 4) void gramA_kernel(
    const short* __restrict__ F, float* __restrict__ partials)
{
    __shared__ __align__(16) short ldsA[64 * LSTR];
    __shared__ __align__(16) short ldsB[64 * LSTR];

    const int id = blockIdx.x;
    const int t = threadIdx.x, w = t >> 6, lane = t & 63;
    const int r16 = lane & 15, quad = lane >> 4;

    float4v acc[2][2];
#pragma unroll
    for (int i = 0; i < 2; ++i)
#pragma unroll
        for (int j = 0; j < 2; ++j) acc[i][j] = (float4v){0.f, 0.f, 0.f, 0.f};

    if (id < 320) {                      // group 1: c=128, hw=4096
        const int comb = id >> 5, sub = id & 31;
        const int b = sub >> 3, ks = sub & 7;
        const int g = g1_tab[comb][0];
        const int ra = g1_tab[comb][1] << 6, rb = g1_tab[comb][2] << 6;
        const short* Fa = (g == 1 ? F + F1S : F + F1T) + (size_t)(b * 128 + ra) * 4096;
        const short* Fb = (g == 0 ? F + F1T : F + F1S) + (size_t)(b * 128 + rb) * 4096;
        const int k0 = ks * 512;
        if (g < 2 && ra == rb) gram_tile<4096, true >(Fa, Fa, k0, t, ldsA, ldsB, acc);
        else                   gram_tile<4096, false>(Fa, Fb, k0, t, ldsA, ldsB, acc);
    } else {                             // group 2: c=256, hw=1024
        const int id2 = id - 320;
        const int comb = id2 >> 3, sub = id2 & 7;
        const int b = sub >> 1, ks = sub & 1;
        const int g = g2_tab[comb][0];
        const int ra = g2_tab[comb][1] << 6, rb = g2_tab[comb][2] << 6;
        const short* Fa = (g == 1 ? F + F2S : F + F2T) + (size_t)(b * 256 + ra) * 1024;
        const short* Fb = (g == 0 ? F + F2T : F + F2S) + (size_t)(b * 256 + rb) * 1024;
        const int k0 = ks * 512;
        if (g < 2 && ra == rb) gram_tile<1024, true >(Fa, Fa, k0, t, ldsA, ldsB, acc);
        else                   gram_tile<1024, false>(Fa, Fb, k0, t, ldsA, ldsB, acc);
    }

    // ---- write 64x64 fp32 k-partial; wave-owned strips, no combine --------
    // C/D layout: col = lane&15, row = quad*4 + reg.
    float* dst = partials + (size_t)id * 4096;
    const int rt2 = (w >> 1) * 2, ct2 = (w & 1) * 2;
#pragma unroll
    for (int i = 0; i < 2; ++i)
#pragma unroll
        for (int j = 0; j < 2; ++j)
#pragma unroll
            for (int r = 0; r < 4; ++r)
                dst[((rt2 + i) * 16 + quad * 4 + r) * 64 + (ct2 + j) * 16 + r16]
                    = acc[i][j][r];
}

// ------------- stage B: 184 blocks; sum k-partials, square, weight ---------
template<int P>
__device__ inline float gramB_sum(const float* __restrict__ base, int t)
{
    float s = 0.f;
#pragma unroll
    for (int i = 0; i < 4; ++i) {
        const int c4 = i * 1024 + t * 4; // float4 lane-consecutive: coalesced
        float4 v = {0.f, 0.f, 0.f, 0.f};
#pragma unroll
        for (int p = 0; p < P; ++p) {
            float4 u = *(const float4*)(base + (size_t)p * 4096 + c4);
            v.x += u.x; v.y += u.y; v.z += u.z; v.w += u.w;
        }
        s += v.x * v.x + v.y * v.y + v.z * v.z + v.w * v.w;
    }
    return s;
}

__global__ __launch_bounds__(256) void gramB_kernel(
    const float* __restrict__ partials, float* __restrict__ out)
{
    __shared__ float scratch[256];
    const int tile = blockIdx.x, t = threadIdx.x;
    float s, wt; int which;
    if (tile < 40) {
        const int comb = tile >> 2, b = tile & 3;
        s = gramB_sum<8>(partials + (size_t)(comb * 32 + b * 8) * 4096, t);
        wt = (float)g1_tab[comb][3] * (1.0f / (4096.f * 4096.f * 4.f));
        which = 2;
    } else {
        const int t2 = tile - 40;
        const int comb = t2 >> 2, b = t2 & 3;
        s = gramB_sum<2>(partials + (size_t)(320 + comb * 8 + b * 2) * 4096, t);
        wt = (float)g2_tab[comb][3] * (1.0f / (1024.f * 1024.f * 4.f));
        which = 3;
    }
    s *= wt;
    scratch[t] = s;
    __syncthreads();
    for (int off = 128; off > 0; off >>= 1) {
        if (t < off) scratch[t] += scratch[t + off];
        __syncthreads();
    }
    if (t == 0) {
        float v = scratch[0];
        atomicAdd(&out[0], v);           // loss
        atomicAdd(&out[1], v);           // stack[0] = loss
        atomicAdd(&out[which], v);       // stack[1]=pwl_g1 / stack[2]=pwl_g2
    }
}

extern "C" void kernel_launch(void* const* d_in, const int* in_sizes, int n_in,
                              void* d_out, int out_size, void* d_ws, size_t ws_size,
                              hipStream_t stream)
{
    const float* x1t = (const float*)d_in[0];   // [4,128,64,64]
    const float* x1s = (const float*)d_in[1];
    const float* x2t = (const float*)d_in[2];   // [4,256,32,32]
    const float* x2s = (const float*)d_in[3];

    short* F        = (short*)d_ws;              // 6291456 shorts (12.6 MB)
    float* partials = (float*)d_ws + 3200000;    // 608 x 4096 floats (10 MB)

    prep_kernel<<<1280, 256, 0, stream>>>(x1t, x1s, x2t, x2s, F, (float*)d_out);
    gramA_kernel<<<608, 256, 0, stream>>>(F, partials);
    gramB_kernel<<<184, 256, 0, stream>>>(partials, (float*)d_out);
}